// Round 10
// baseline (340.142 us; speedup 1.0000x reference)
//
#include <hip/hip_runtime.h>
#include <stdint.h>

// Tree-LSTM scan: B=256, L=128, STATE=128, INIT=256, Z=5*128=640. fp32 I/O.
// Pipeline:
//  k0: whx_w fp32 -> bf16 (row-major 640x256) into d_ws.
//  k1: zx[t*256+b] = bias + Wx * right_h(embed[ids[b][t]])  (full-GPU GEMM,
//      M=32768 N=640 K=128), stored bf16 with right_c appended: row =
//      [z 640 | rc 128 | pad 8]. ws ~= 256 MB (fillBuffer evidence), zx 48.5 MB.
//  k2: scan, 16 blocks x 512 thr. In-loop: 20 MFMA/wave (h-half only),
//      4 ds_read_b128/wave, z+rc via register prefetch (global, 1 step ahead),
//      RAW barrier (s_waitcnt lgkmcnt(0); s_barrier) so the prefetch is never
//      drained by the per-step barrier (__syncthreads would force vmcnt(0)).

constexpr int kL      = 128;
constexpr int kState  = 128;
constexpr int kInit   = 256;
constexpr int kRows   = 16;
constexpr int kBlocks = 16;
constexpr int kThreads= 512;
constexpr int kWElems = 5 * kState * kInit;     // 163840 (320 KiB bf16)
constexpr int kZStr   = 776;                    // zx row elems: 640 z | 128 rc | 8 pad
constexpr int kMRows  = 256 * kL;               // 32768 (t,b) rows

typedef __attribute__((ext_vector_type(8))) short short8;    // MFMA A/B frag
typedef __attribute__((ext_vector_type(4))) short short4v;
typedef __attribute__((ext_vector_type(4))) float floatx4;   // MFMA C/D frag

__device__ __forceinline__ uint16_t f2bf(float f) {
    union { float f; uint32_t i; } v; v.f = f;
    return (uint16_t)((v.i + 0x7FFFu + ((v.i >> 16) & 1u)) >> 16);  // RNE
}
__device__ __forceinline__ float bf2f(uint16_t u) {
    union { uint32_t i; float f; } v; v.i = ((uint32_t)u) << 16; return v.f;
}
__device__ __forceinline__ short8 cvt8(const float* p) {
    float4 a = ((const float4*)p)[0];
    float4 b = ((const float4*)p)[1];
    short8 r;
    r[0]=f2bf(a.x); r[1]=f2bf(a.y); r[2]=f2bf(a.z); r[3]=f2bf(a.w);
    r[4]=f2bf(b.x); r[5]=f2bf(b.y); r[6]=f2bf(b.z); r[7]=f2bf(b.w);
    return r;
}
__device__ __forceinline__ float clampf(float x, float lo, float hi) {
    return fminf(fmaxf(x, lo), hi);
}

// ---- kernel 0: whx_w fp32 -> bf16 ----
__global__ __launch_bounds__(256)
void convert_weights_kernel(const float* __restrict__ wsrc,
                            uint16_t* __restrict__ wdst) {
    int i = blockIdx.x * 256 + threadIdx.x;          // float4 index
    float4 v = ((const float4*)wsrc)[i];
    uint16_t q[4] = { f2bf(v.x), f2bf(v.y), f2bf(v.z), f2bf(v.w) };
    ((short4v*)wdst)[i] = *(short4v*)q;
}

// ---- kernel 1: zx GEMM + rc copy. 512 blocks x 512 thr, 4 rowgroups/block.
// Row m = t*256 + b. Rowgroup = 16 consecutive rows (same t, b = bb..bb+16).
__global__ __launch_bounds__(512)
void zx_gemm_kernel(const int* __restrict__ ids,
                    const float* __restrict__ embed,
                    const uint16_t* __restrict__ wbf,
                    const float* __restrict__ whx_b,
                    uint16_t* __restrict__ zx)
{
    const int tid  = threadIdx.x;
    const int w    = tid >> 6;
    const int lane = tid & 63;
    const int l15  = lane & 15;
    const int quad = lane >> 4;
    const int j0   = w * 16 + quad * 4;

#pragma unroll 1
    for (int rg = 0; rg < 4; ++rg) {
        const int rowbase = blockIdx.x * 64 + rg * 16;
        const int t  = rowbase >> 8;
        const int bb = rowbase & 255;
        const int id = ids[(bb + l15) * kL + t];

        floatx4 acc[5];
#pragma unroll
        for (int g = 0; g < 5; ++g)
            acc[g] = *(const floatx4*)(whx_b + g * 128 + j0);

#pragma unroll
        for (int kk = 0; kk < 4; ++kk) {
            // B-frag: right_h = embed[id][0:128], k = kk*32 + quad*8 + [0..8)
            short8 xf = cvt8(embed + (size_t)id * kInit + kk * 32 + quad * 8);
#pragma unroll
            for (int g = 0; g < 5; ++g) {
                // A-frag: Wx = W cols 128..256, row g*128 + w*16 + l15
                short8 af = *(const short8*)(wbf +
                    (size_t)(g * 128 + w * 16 + l15) * kInit + 128 + kk * 32 + quad * 8);
                acc[g] = __builtin_amdgcn_mfma_f32_16x16x32_bf16(af, xf, acc[g], 0, 0, 0);
            }
        }
        // D: col=l15 -> data row rowbase+l15; row=quad*4+r -> j0+r
        uint16_t* zrow = zx + (size_t)(rowbase + l15) * kZStr;
#pragma unroll
        for (int g = 0; g < 5; ++g) {
            uint16_t q[4] = { f2bf(acc[g][0]), f2bf(acc[g][1]),
                              f2bf(acc[g][2]), f2bf(acc[g][3]) };
            *(short4v*)(zrow + g * 128 + j0) = *(short4v*)q;
        }
        // rc copy: right_c = embed[id][128:256] -> zx row cols 640..768
        {
            int rrow = tid >> 5;              // 0..15
            int e    = (tid & 31) * 4;        // 0..124
            int id2  = ids[(bb + rrow) * kL + t];
            float4 v = *(const float4*)(embed + (size_t)id2 * kInit + 128 + e);
            uint16_t q[4] = { f2bf(v.x), f2bf(v.y), f2bf(v.z), f2bf(v.w) };
            *(short4v*)(zx + (size_t)(rowbase + rrow) * kZStr + 640 + e) = *(short4v*)q;
        }
    }
}

// ---- kernel 2: the scan ----
__global__ __launch_bounds__(kThreads)
__attribute__((amdgpu_waves_per_eu(1, 2)))
void tree_lstm_kernel(const uint16_t* __restrict__ wbf,
                      const uint16_t* __restrict__ zx,
                      const float* __restrict__ init_state,
                      const float* __restrict__ final_w,
                      const float* __restrict__ final_b,
                      const int* __restrict__ ids,
                      float* __restrict__ out)
{
    // h: element (row,col) at [row][ ((col>>3)^row)*8 + (col&7) ] (R9-proven)
    __shared__ alignas(16) uint16_t hb[2][kRows][kState];   // 8 KB
    __shared__ float partial[kRows][3][4];
    // >80 KiB total => compiler models 1 WG/CU => 256-reg unified budget
    // (mechanism validated R6-R8; kept alive via unprovable volatile use).
    __shared__ float lds_force_pad[18944];                  // 74 KiB

    const int tid  = threadIdx.x;
    const int w    = tid >> 6;
    const int lane = tid & 63;
    const int l15  = lane & 15;
    const int quad = lane >> 4;
    const int b0   = blockIdx.x * kRows;
    const int j0   = w * 16 + quad * 4;

    if (__builtin_expect(ids[0] < 0, 0)) {      // never true; keeps pad alive
        volatile float* vp = lds_force_pad;
        vp[tid] = (float)tid;
        float v = vp[(tid * 7) & 18943];
        if (v < -1.0e30f) out[0] = v;
    }

    // register-resident A-frags, h-half of W only: wf[5][4] = 80 VGPRs
    short8 wf[5][4];
#pragma unroll
    for (int g = 0; g < 5; ++g) {
        const uint16_t* wrow = wbf + (size_t)(g * 128 + w * 16 + l15) * kInit;
#pragma unroll
        for (int kk = 0; kk < 4; ++kk)
            wf[g][kk] = *(const short8*)(wrow + kk * 32 + quad * 8);
    }

    // h0 (bf16, swizzled) and c0 (fp32 regs), broadcast over batch
    const int ch2  = 2 * w + (quad >> 1);
    const int hoff = (ch2 ^ l15) * 8 + (quad & 1) * 4;
    float c_reg[4];
    {
        uint16_t h0[4];
#pragma unroll
        for (int r = 0; r < 4; ++r) {
            h0[r]    = f2bf(init_state[j0 + r]);
            c_reg[r] = init_state[128 + j0 + r];
        }
        *(short4v*)&hb[0][l15][hoff] = *(short4v*)h0;
    }

    // prologue prefetch: z + rc for t=0 (row b0+l15), 6 x 8B register loads
    const size_t rowstep = (size_t)256 * kZStr;             // elems per t
    const uint16_t* zrow = zx + (size_t)(b0 + l15) * kZStr; // t=0 row
    short4v zpre[5], rcpre;
#pragma unroll
    for (int g = 0; g < 5; ++g)
        zpre[g] = *(const short4v*)(zrow + g * 128 + j0);
    rcpre = *(const short4v*)(zrow + 640 + j0);
    const uint16_t* znext = zrow + rowstep;                 // t=1 row

    __syncthreads();

    const float K1 = 1.442695041f;   // log2(e)
    const float K2 = 2.885390082f;   // 2*log2(e)

#pragma unroll 1
    for (int t = 0; t < kL; ++t) {
        const int cur = t & 1, nxt = cur ^ 1;

        // consume prefetch: acc init = z (bias + Wx*x already inside)
        floatx4 acc[5];
#pragma unroll
        for (int g = 0; g < 5; ++g) {
#pragma unroll
            for (int r = 0; r < 4; ++r) acc[g][r] = bf2f((uint16_t)zpre[g][r]);
        }
        float rcv[4];
#pragma unroll
        for (int r = 0; r < 4; ++r) rcv[r] = bf2f((uint16_t)rcpre[r]);

        // issue prefetch for t+1 (stays in flight across the raw barrier)
#pragma unroll
        for (int g = 0; g < 5; ++g)
            zpre[g] = *(const short4v*)(znext + g * 128 + j0);
        rcpre = *(const short4v*)(znext + 640 + j0);
        if (t + 2 < kL) znext += rowstep;

        // MFMA: h-half, K=128
        const uint16_t* hrow = &hb[cur][l15][0];
#pragma unroll
        for (int kk = 0; kk < 4; ++kk) {
            short8 xf = *(const short8*)(hrow + ((kk * 4 + quad) ^ l15) * 8);
#pragma unroll
            for (int g = 0; g < 5; ++g)
                acc[g] = __builtin_amdgcn_mfma_f32_16x16x32_bf16(wf[g][kk], xf, acc[g], 0, 0, 0);
        }

        // gates: lane owns (b=l15, j=j0..j0+3)
        uint16_t hv[4];
#pragma unroll
        for (int r = 0; r < 4; ++r) {
            float a  = clampf(acc[0][r], -15.f, 15.f);
            float ii = clampf(acc[1][r], -30.f, 30.f);
            float f1 = clampf(acc[2][r], -30.f, 30.f);
            float f2 = clampf(acc[3][r], -30.f, 30.f);
            float oo = clampf(acc[4][r], -30.f, 30.f);

            float Ea = exp2f(a * K2);                 // e^{2a}
            float Ei = exp2f(-ii * K1);               // e^{-i}
            float P  = (Ea - 1.0f) * __builtin_amdgcn_rcpf((Ea + 1.0f) * (1.0f + Ei));
            float E1 = exp2f(f1 * K1), E2 = exp2f(f2 * K1);
            float lc = c_reg[r], rc = rcv[r];
            float num = E1 * (1.0f + E2) * lc + E2 * (1.0f + E1) * rc;
            float Q  = num * __builtin_amdgcn_rcpf((1.0f + E1) * (1.0f + E2));
            float c  = P + Q;
            c_reg[r] = c;
            float Eo = exp2f(-oo * K1);
            float cc = clampf(c, -15.f, 15.f);
            float Ec = exp2f(cc * K2);
            float h  = (Ec - 1.0f) * __builtin_amdgcn_rcpf((1.0f + Eo) * (Ec + 1.0f));
            hv[r] = f2bf(h);
        }
        *(short4v*)&hb[nxt][l15][hoff] = *(short4v*)hv;

        // RAW barrier: wait LDS ops only (h visibility); the global z/rc
        // prefetch is NOT drained (a plain __syncthreads would vmcnt(0) it).
        __asm__ volatile("s_waitcnt lgkmcnt(0)\n\ts_barrier" ::: "memory");
    }
    __syncthreads();

    // final: out[b][o] = sum_j h[b][j]*final_w[o][j] + final_b[o]
    // final h is in hb[0] (t=127 wrote nxt=0), swizzled
    if (tid < 192) {
        int b = tid / 12, rem = tid % 12;
        int o = rem >> 2, q4 = rem & 3;
        float s = 0.f;
        const float* wrow = final_w + o * kState;
#pragma unroll 8
        for (int j = q4 * 32; j < q4 * 32 + 32; ++j) {
            uint16_t hval = hb[0][b][((j >> 3) ^ b) * 8 + (j & 7)];
            s += bf2f(hval) * wrow[j];
        }
        partial[b][o][q4] = s;
    }
    __syncthreads();
    if (tid < 48) {
        int b = tid / 3, o = tid % 3;
        float s = partial[b][o][0] + partial[b][o][1] +
                  partial[b][o][2] + partial[b][o][3] + final_b[o];
        out[(b0 + b) * 3 + o] = s;
    }
}

extern "C" void kernel_launch(void* const* d_in, const int* in_sizes, int n_in,
                              void* d_out, int out_size, void* d_ws, size_t ws_size,
                              hipStream_t stream) {
    const int*   ids        = (const int*)d_in[0];
    const float* embed      = (const float*)d_in[1];
    const float* whx_w      = (const float*)d_in[2];
    const float* whx_b      = (const float*)d_in[3];
    const float* init_state = (const float*)d_in[4];
    const float* final_w    = (const float*)d_in[5];
    const float* final_b    = (const float*)d_in[6];
    float*       out        = (float*)d_out;
    uint16_t*    wbf        = (uint16_t*)d_ws;          // 320 KiB
    uint16_t*    zx         = wbf + kWElems;            // 48.5 MiB

    convert_weights_kernel<<<kWElems / 4 / 256, 256, 0, stream>>>(whx_w, wbf);
    zx_gemm_kernel<<<kMRows / 64, 512, 0, stream>>>(ids, embed, wbf, whx_b, zx);
    tree_lstm_kernel<<<kBlocks, kThreads, 0, stream>>>(
        wbf, zx, init_state, final_w, final_b, ids, out);
}